// Round 1
// baseline (1936.517 us; speedup 1.0000x reference)
//
#include <hip/hip_runtime.h>
#include <math.h>

#define NH 16
#define SEQ 2048
#define DIM 128
#define NMEM 4096
#define TOPK 16
#define TQ 64          // queries per workgroup
#define KC 32          // keys per chunk
#define NCHUNK (NMEM / KC)
#define QST 132        // Q LDS row stride (pad 4: consecutive-row f4 reads land 2-way -> free)
#define KST 132
#define SST 36         // sims LDS row stride (mult of 4 for b128 alignment)

__global__ __launch_bounds__(256, 2)
void praxis_fused(const float* __restrict__ query,
                  const float* __restrict__ outputs,
                  const float* __restrict__ gate,
                  const float* __restrict__ kmem,
                  const float* __restrict__ vmem,
                  float* __restrict__ out)
{
    // union: phase-a (GEMM) arrays vs phase-b (final top-k merge) arrays
    __shared__ union SM {
        struct { float Qs[TQ * QST]; float Ks[KC * KST]; float Sc[TQ * SST]; } a; // 58.5 KB
        struct { float fs[TQ][64]; int fi[TQ][64]; float tks[TQ][TOPK]; int tki[TQ][TOPK]; } b; // 40 KB
    } sm;

    const int tid = threadIdx.x;
    const int h  = blockIdx.x >> 5;        // 32 q-blocks per head
    const int q0 = (blockIdx.x & 31) * TQ;

    const float* Qg = query + ((size_t)h * SEQ + q0) * DIM;
    const float* Kg = kmem + (size_t)h * NMEM * DIM;
    const float* Vg = vmem + (size_t)h * NMEM * DIM;

    // ---- stage Q tile (64 x 128), coalesced f4 ----
#pragma unroll
    for (int i = 0; i < 8; ++i) {
        int f4 = i * 256 + tid;
        int row = f4 >> 5, col = f4 & 31;
        float4 v = *(const float4*)(Qg + (size_t)f4 * 4);
        *(float4*)(&sm.a.Qs[row * QST + col * 4]) = v;
    }
    __syncthreads();
    // ---- normalize Q rows (ref: x / max(||x||, 1e-6)), 4 threads per row ----
    {
        int row = tid >> 2, part = tid & 3;
        float ss = 0.f;
#pragma unroll
        for (int j = 0; j < 8; ++j) {
            float4 v = *(const float4*)(&sm.a.Qs[row * QST + part * 32 + j * 4]);
            ss = fmaf(v.x, v.x, ss); ss = fmaf(v.y, v.y, ss);
            ss = fmaf(v.z, v.z, ss); ss = fmaf(v.w, v.w, ss);
        }
        ss += __shfl_xor(ss, 1);
        ss += __shfl_xor(ss, 2);
        float inv = 1.0f / fmaxf(sqrtf(ss), 1e-6f);
#pragma unroll
        for (int j = 0; j < 8; ++j) {
            float4* p = (float4*)(&sm.a.Qs[row * QST + part * 32 + j * 4]);
            float4 v = *p;
            v.x *= inv; v.y *= inv; v.z *= inv; v.w *= inv;
            *p = v;
        }
    }

    // per-thread running top-16 over this thread's disjoint key subset
    // thread = (row = tid>>2, part = tid&3); subset = keys with (k%32) in [part*8, part*8+8)
    float ls[TOPK]; int li[TOPK];
#pragma unroll
    for (int t = 0; t < TOPK; ++t) { ls[t] = -1e30f; li[t] = 0; }
    float mn = -1e30f;

    // preload K chunk 0 into registers
    float4 kreg[4];
#pragma unroll
    for (int j = 0; j < 4; ++j)
        kreg[j] = *(const float4*)(Kg + (size_t)(j * 256 + tid) * 4);

    for (int c = 0; c < NCHUNK; ++c) {
        // stage K chunk regs -> LDS
#pragma unroll
        for (int j = 0; j < 4; ++j) {
            int f4 = j * 256 + tid;
            int row = f4 >> 5, col = f4 & 31;
            *(float4*)(&sm.a.Ks[row * KST + col * 4]) = kreg[j];
        }
        __syncthreads();  // A: Ks staged (also covers Q-normalize on first iter)

        // normalize K chunk rows: 8 threads per key, 16 dims each
        {
            int key = tid >> 3, part = tid & 7;
            float ss = 0.f;
#pragma unroll
            for (int j = 0; j < 4; ++j) {
                float4 v = *(const float4*)(&sm.a.Ks[key * KST + part * 16 + j * 4]);
                ss = fmaf(v.x, v.x, ss); ss = fmaf(v.y, v.y, ss);
                ss = fmaf(v.z, v.z, ss); ss = fmaf(v.w, v.w, ss);
            }
            ss += __shfl_xor(ss, 1);
            ss += __shfl_xor(ss, 2);
            ss += __shfl_xor(ss, 4);
            float inv = 1.0f / fmaxf(sqrtf(ss), 1e-6f);
#pragma unroll
            for (int j = 0; j < 4; ++j) {
                float4* p = (float4*)(&sm.a.Ks[key * KST + part * 16 + j * 4]);
                float4 v = *p;
                v.x *= inv; v.y *= inv; v.z *= inv; v.w *= inv;
                *p = v;
            }
        }
        __syncthreads();  // B: Ks normalized

        // prefetch next chunk (overlaps with compute below)
        if (c + 1 < NCHUNK) {
            const float* base = Kg + (size_t)(c + 1) * KC * DIM;
#pragma unroll
            for (int j = 0; j < 4; ++j)
                kreg[j] = *(const float4*)(base + (size_t)(j * 256 + tid) * 4);
        }

        // ---- sims GEMM: micro-tile 4q x 2k, strided rows (bank-conflict-free) ----
        {
            int qg = tid >> 4, kg = tid & 15;
            float acc[4][2];
#pragma unroll
            for (int i = 0; i < 4; ++i)
#pragma unroll
                for (int j = 0; j < 2; ++j) acc[i][j] = 0.f;
#pragma unroll 4
            for (int d4 = 0; d4 < 32; ++d4) {
                float4 qa[4], kb[2];
#pragma unroll
                for (int i = 0; i < 4; ++i)
                    qa[i] = *(const float4*)(&sm.a.Qs[(qg + 16 * i) * QST + d4 * 4]);
#pragma unroll
                for (int j = 0; j < 2; ++j)
                    kb[j] = *(const float4*)(&sm.a.Ks[(kg + 16 * j) * KST + d4 * 4]);
#pragma unroll
                for (int i = 0; i < 4; ++i)
#pragma unroll
                    for (int j = 0; j < 2; ++j) {
                        acc[i][j] = fmaf(qa[i].x, kb[j].x, acc[i][j]);
                        acc[i][j] = fmaf(qa[i].y, kb[j].y, acc[i][j]);
                        acc[i][j] = fmaf(qa[i].z, kb[j].z, acc[i][j]);
                        acc[i][j] = fmaf(qa[i].w, kb[j].w, acc[i][j]);
                    }
            }
#pragma unroll
            for (int i = 0; i < 4; ++i)
#pragma unroll
                for (int j = 0; j < 2; ++j)
                    sm.a.Sc[(qg + 16 * i) * SST + kg + 16 * j] = acc[i][j];
        }
        __syncthreads();  // C: sims ready

        // ---- parallel top-k merge: each thread filters its 8 sims ----
        {
            int row = tid >> 2, part = tid & 3;
            float4 s0 = *(const float4*)(&sm.a.Sc[row * SST + part * 8]);
            float4 s1 = *(const float4*)(&sm.a.Sc[row * SST + part * 8 + 4]);
            float cand[8] = { s0.x, s0.y, s0.z, s0.w, s1.x, s1.y, s1.z, s1.w };
            int kb0 = c * KC + part * 8;
#pragma unroll
            for (int j = 0; j < 8; ++j) {
                float s = cand[j];
                if (s > mn) {
                    int am = 0; float mv = ls[0];
#pragma unroll
                    for (int t = 1; t < TOPK; ++t)
                        if (ls[t] < mv) { mv = ls[t]; am = t; }
#pragma unroll
                    for (int t = 0; t < TOPK; ++t)
                        if (t == am) { ls[t] = s; li[t] = kb0 + j; }
                    mn = ls[0];
#pragma unroll
                    for (int t = 1; t < TOPK; ++t) mn = fminf(mn, ls[t]);
                }
            }
        }
        // no barrier: next iter writes Ks (disjoint from Sc); barrier A orders Sc reuse
    }

    __syncthreads();  // all merges complete before reusing LDS as phase-b
    // dump partial top-16 lists: 64 candidates per row
    {
        int row = tid >> 2, part = tid & 3;
#pragma unroll
        for (int t = 0; t < TOPK; ++t) {
            sm.b.fs[row][part * TOPK + t] = ls[t];
            sm.b.fi[row][part * TOPK + t] = li[t];
        }
    }
    __syncthreads();
    // final selection: one wave per 16 rows, 16 iterations of wave-max over 64 candidates
    {
        int wv = tid >> 6, lane = tid & 63;
        for (int rr = 0; rr < 16; ++rr) {
            int row = wv * 16 + rr;
            float s = sm.b.fs[row][lane];
            int  id = sm.b.fi[row][lane];
#pragma unroll 1
            for (int it = 0; it < TOPK; ++it) {
                float m = s;
#pragma unroll
                for (int off = 32; off >= 1; off >>= 1)
                    m = fmaxf(m, __shfl_xor(m, off));
                unsigned long long bal = __ballot(s == m);
                int who = (int)__ffsll(bal) - 1;
                int selid = __shfl(id, who);
                if (lane == 0) { sm.b.tks[row][it] = m; sm.b.tki[row][it] = selid; }
                if (lane == who) s = -3e38f;   // remove from future rounds
            }
        }
    }
    __syncthreads();
    // ---- epilogue: gather V, weighted sum (descending-score order = ref order), gate blend ----
    {
        int row = tid >> 2, part = tid & 3;
        float4 acc[8];
#pragma unroll
        for (int j = 0; j < 8; ++j) acc[j] = make_float4(0.f, 0.f, 0.f, 0.f);
#pragma unroll 1
        for (int t = 0; t < TOPK; ++t) {
            float s = sm.b.tks[row][t];
            int idx = sm.b.tki[row][t];
            const float* vp = Vg + (size_t)idx * DIM + part * 32;
#pragma unroll
            for (int j = 0; j < 8; ++j) {
                float4 v = *(const float4*)(vp + j * 4);
                acc[j].x = fmaf(s, v.x, acc[j].x);
                acc[j].y = fmaf(s, v.y, acc[j].y);
                acc[j].z = fmaf(s, v.z, acc[j].z);
                acc[j].w = fmaf(s, v.w, acc[j].w);
            }
        }
        float g = 1.0f / (1.0f + expf(-gate[h]));
        float og = 1.0f - g;
        size_t ob = ((size_t)h * SEQ + q0 + row) * DIM + part * 32;
#pragma unroll
        for (int j = 0; j < 8; ++j) {
            float4 o = *(const float4*)(outputs + ob + j * 4);
            float4 r;
            r.x = g * acc[j].x + og * o.x;
            r.y = g * acc[j].y + og * o.y;
            r.z = g * acc[j].z + og * o.z;
            r.w = g * acc[j].w + og * o.w;
            *(float4*)(out + ob + j * 4) = r;
        }
    }
}

extern "C" void kernel_launch(void* const* d_in, const int* in_sizes, int n_in,
                              void* d_out, int out_size, void* d_ws, size_t ws_size,
                              hipStream_t stream) {
    (void)in_sizes; (void)n_in; (void)out_size; (void)d_ws; (void)ws_size;
    const float* query   = (const float*)d_in[1];
    const float* outputs = (const float*)d_in[4];
    const float* gate    = (const float*)d_in[5];
    const float* kmem    = (const float*)d_in[6];
    const float* vmem    = (const float*)d_in[7];
    float* out = (float*)d_out;
    dim3 grid(NH * (SEQ / TQ));  // 512 workgroups, 2 per CU
    praxis_fused<<<grid, 256, 0, stream>>>(query, outputs, gate, kmem, vmem, out);
}

// Round 3
// 1395.159 us; speedup vs baseline: 1.3880x; 1.3880x over previous
//
#include <hip/hip_runtime.h>
#include <math.h>

#define NH 16
#define SEQ 2048
#define DIM 128
#define NMEM 4096
#define TOPK 16
#define TQ 128         // queries per workgroup
#define KC 64          // keys per chunk
#define NCHUNK (NMEM / KC)   // 64
#define QST 132        // Q LDS row stride (pad 4 -> <=2-way aliasing, free)
#define KST 132
#define SST 68         // sims LDS row stride; 68*4=272 B == 0 mod 16 -> b128-aligned every row
#define NTHR 512

__global__ __launch_bounds__(NTHR, 2)
void praxis_fused(const float* __restrict__ query,
                  const float* __restrict__ outputs,
                  const float* __restrict__ gate,
                  const float* __restrict__ kmem,
                  const float* __restrict__ vmem,
                  float* __restrict__ out)
{
    __shared__ union SM {
        struct { float Qs[TQ * QST]; float Ks[KC * KST]; float Sc[TQ * SST]; } a; // 133 KB
        struct { float fs[TQ][64]; int fi[TQ][64]; float tks[TQ][TOPK]; int tki[TQ][TOPK]; } b; // 80 KB
    } sm;

    const int tid = threadIdx.x;
    const int h  = blockIdx.x >> 4;        // 16 q-tiles per head (SEQ/TQ)
    const int q0 = (blockIdx.x & 15) * TQ;

    const float* Qg = query + ((size_t)h * SEQ + q0) * DIM;
    const float* Kg = kmem + (size_t)h * NMEM * DIM;
    const float* Vg = vmem + (size_t)h * NMEM * DIM;

    // ---- stage Q tile (128 x 128), coalesced f4 ----
#pragma unroll
    for (int i = 0; i < 8; ++i) {
        int f4 = i * NTHR + tid;
        int row = f4 >> 5, col = f4 & 31;
        float4 v = *(const float4*)(Qg + (size_t)f4 * 4);
        *(float4*)(&sm.a.Qs[row * QST + col * 4]) = v;
    }
    __syncthreads();
    // ---- normalize Q rows (ref: x / max(||x||,1e-6)), 4 threads/row ----
    {
        int row = tid >> 2, part = tid & 3;
        float ss = 0.f;
#pragma unroll
        for (int j = 0; j < 8; ++j) {
            float4 v = *(const float4*)(&sm.a.Qs[row * QST + part * 32 + j * 4]);
            ss = fmaf(v.x, v.x, ss); ss = fmaf(v.y, v.y, ss);
            ss = fmaf(v.z, v.z, ss); ss = fmaf(v.w, v.w, ss);
        }
        ss += __shfl_xor(ss, 1);
        ss += __shfl_xor(ss, 2);
        float inv = 1.0f / fmaxf(sqrtf(ss), 1e-6f);
#pragma unroll
        for (int j = 0; j < 8; ++j) {
            float4* p = (float4*)(&sm.a.Qs[row * QST + part * 32 + j * 4]);
            float4 v = *p;
            v.x *= inv; v.y *= inv; v.z *= inv; v.w *= inv;
            *p = v;
        }
    }

    // per-thread running top-16 (SORTED ascending; ls[0] is the threshold)
    float ls[TOPK]; int li[TOPK];
#pragma unroll
    for (int t = 0; t < TOPK; ++t) { ls[t] = -1e30f; li[t] = 0; }

    // preload K chunk 0 (64 keys x 128 dims = 2048 f4 / 512 thr = 4 each)
    float4 kreg[4];
#pragma unroll
    for (int j = 0; j < 4; ++j)
        kreg[j] = *(const float4*)(Kg + (size_t)(j * NTHR + tid) * 4);

    for (int c = 0; c < NCHUNK; ++c) {
        // stage K chunk regs -> LDS
#pragma unroll
        for (int j = 0; j < 4; ++j) {
            int f4 = j * NTHR + tid;
            int row = f4 >> 5, col = f4 & 31;
            *(float4*)(&sm.a.Ks[row * KST + col * 4]) = kreg[j];
        }
        __syncthreads();  // A

        // normalize K rows: 8 threads/key
        {
            int key = tid >> 3, part = tid & 7;
            float ss = 0.f;
#pragma unroll
            for (int j = 0; j < 4; ++j) {
                float4 v = *(const float4*)(&sm.a.Ks[key * KST + part * 16 + j * 4]);
                ss = fmaf(v.x, v.x, ss); ss = fmaf(v.y, v.y, ss);
                ss = fmaf(v.z, v.z, ss); ss = fmaf(v.w, v.w, ss);
            }
            ss += __shfl_xor(ss, 1);
            ss += __shfl_xor(ss, 2);
            ss += __shfl_xor(ss, 4);
            float inv = 1.0f / fmaxf(sqrtf(ss), 1e-6f);
#pragma unroll
            for (int j = 0; j < 4; ++j) {
                float4* p = (float4*)(&sm.a.Ks[key * KST + part * 16 + j * 4]);
                float4 v = *p;
                v.x *= inv; v.y *= inv; v.z *= inv; v.w *= inv;
                *p = v;
            }
        }
        __syncthreads();  // B

        // prefetch next chunk (in flight across GEMM)
        if (c + 1 < NCHUNK) {
            const float* base = Kg + (size_t)(c + 1) * KC * DIM;
#pragma unroll
            for (int j = 0; j < 4; ++j)
                kreg[j] = *(const float4*)(base + (size_t)(j * NTHR + tid) * 4);
        }

        // ---- sims GEMM: 4q x 4k per thread (512 thr = 32 qg x 16 kg) ----
        // Q reads: 4 distinct addrs/wave (broadcast, conflict-free);
        // K reads: 16 distinct addrs/wave, 2-way bank alias (free, m136).
        {
            int qg = tid >> 4, kg = tid & 15;
            float acc[4][4];
#pragma unroll
            for (int i = 0; i < 4; ++i)
#pragma unroll
                for (int j = 0; j < 4; ++j) acc[i][j] = 0.f;
#pragma unroll 4
            for (int d4 = 0; d4 < 32; ++d4) {
                float4 qa[4], kb[4];
#pragma unroll
                for (int i = 0; i < 4; ++i)
                    qa[i] = *(const float4*)(&sm.a.Qs[(qg + 32 * i) * QST + d4 * 4]);
#pragma unroll
                for (int j = 0; j < 4; ++j)
                    kb[j] = *(const float4*)(&sm.a.Ks[(kg + 16 * j) * KST + d4 * 4]);
#pragma unroll
                for (int i = 0; i < 4; ++i)
#pragma unroll
                    for (int j = 0; j < 4; ++j) {
                        acc[i][j] = fmaf(qa[i].x, kb[j].x, acc[i][j]);
                        acc[i][j] = fmaf(qa[i].y, kb[j].y, acc[i][j]);
                        acc[i][j] = fmaf(qa[i].z, kb[j].z, acc[i][j]);
                        acc[i][j] = fmaf(qa[i].w, kb[j].w, acc[i][j]);
                    }
            }
#pragma unroll
            for (int i = 0; i < 4; ++i)
#pragma unroll
                for (int j = 0; j < 4; ++j)
                    sm.a.Sc[(qg + 32 * i) * SST + kg + 16 * j] = acc[i][j];
        }
        __syncthreads();  // C: sims ready

        // ---- top-k filter: max-extract per 4-candidate group ----
        {
            int row = tid >> 2, part = tid & 3;
            const float* scr = &sm.a.Sc[row * SST + part * 16];
            float4 vv[4];
#pragma unroll
            for (int g = 0; g < 4; ++g)
                vv[g] = *(const float4*)(scr + g * 4);
            float mnv = ls[0];
#pragma unroll
            for (int g = 0; g < 4; ++g) {
                float4 v = vv[g];
                int b0 = c * KC + part * 16 + g * 4;
                float m01 = fmaxf(v.x, v.y); int i01 = (v.x >= v.y) ? 0 : 1;
                float m23 = fmaxf(v.z, v.w); int i23 = (v.z >= v.w) ? 2 : 3;
                float m   = fmaxf(m01, m23); int im  = (m01 >= m23) ? i01 : i23;
                while (__ballot(m > mnv)) {
                    if (m > mnv) {
                        // sorted insert (evict ls[0])
                        float s = m; int id = b0 + im;
                        bool bp = true;
#pragma unroll
                        for (int t = 0; t < TOPK - 1; ++t) {
                            bool bt = s > ls[t + 1];
                            float nv = bt ? ls[t + 1] : (bp ? s : ls[t]);
                            int   ni = bt ? li[t + 1] : (bp ? id : li[t]);
                            ls[t] = nv; li[t] = ni; bp = bt;
                        }
                        ls[TOPK - 1] = bp ? s : ls[TOPK - 1];
                        li[TOPK - 1] = bp ? id : li[TOPK - 1];
                        mnv = ls[0];
                        v.x = (im == 0) ? -3e38f : v.x;
                        v.y = (im == 1) ? -3e38f : v.y;
                        v.z = (im == 2) ? -3e38f : v.z;
                        v.w = (im == 3) ? -3e38f : v.w;
                        m01 = fmaxf(v.x, v.y); i01 = (v.x >= v.y) ? 0 : 1;
                        m23 = fmaxf(v.z, v.w); i23 = (v.z >= v.w) ? 2 : 3;
                        m   = fmaxf(m01, m23); im  = (m01 >= m23) ? i01 : i23;
                    }
                }
            }
        }
        // no barrier: next iter writes Ks (disjoint from Sc); barrier A orders reuse
    }

    __syncthreads();  // repurpose LDS as phase-b
    {
        int row = tid >> 2, part = tid & 3;
#pragma unroll
        for (int t = 0; t < TOPK; ++t) {
            sm.b.fs[row][part * TOPK + t] = ls[t];
            sm.b.fi[row][part * TOPK + t] = li[t];
        }
    }
    __syncthreads();
    // final selection: one wave per 16 rows; 16 rounds of wave-max over 64 cands
    {
        int wv = tid >> 6, lane = tid & 63;
        for (int rr = 0; rr < 16; ++rr) {
            int row = wv * 16 + rr;
            float s = sm.b.fs[row][lane];
            int  id = sm.b.fi[row][lane];
#pragma unroll 1
            for (int it = 0; it < TOPK; ++it) {
                float m = s;
#pragma unroll
                for (int off = 32; off >= 1; off >>= 1)
                    m = fmaxf(m, __shfl_xor(m, off));
                unsigned long long bal = __ballot(s == m);
                int who = (int)__ffsll(bal) - 1;
                int selid = __shfl(id, who);
                if (lane == 0) { sm.b.tks[row][it] = m; sm.b.tki[row][it] = selid; }
                if (lane == who) s = -3e38f;
            }
        }
    }
    __syncthreads();
    // ---- epilogue: gather V, weighted sum (descending order = ref order), gate blend ----
    {
        int row = tid >> 2, part = tid & 3;
        float4 acc[8];
#pragma unroll
        for (int j = 0; j < 8; ++j) acc[j] = make_float4(0.f, 0.f, 0.f, 0.f);
#pragma unroll 1
        for (int t = 0; t < TOPK; ++t) {
            float s = sm.b.tks[row][t];
            int idx = sm.b.tki[row][t];
            const float* vp = Vg + (size_t)idx * DIM + part * 32;
#pragma unroll
            for (int j = 0; j < 8; ++j) {
                float4 v = *(const float4*)(vp + j * 4);
                acc[j].x = fmaf(s, v.x, acc[j].x);
                acc[j].y = fmaf(s, v.y, acc[j].y);
                acc[j].z = fmaf(s, v.z, acc[j].z);
                acc[j].w = fmaf(s, v.w, acc[j].w);
            }
        }
        float g = 1.0f / (1.0f + expf(-gate[h]));
        float og = 1.0f - g;
        size_t ob = ((size_t)h * SEQ + q0 + row) * DIM + part * 32;
#pragma unroll
        for (int j = 0; j < 8; ++j) {
            float4 o = *(const float4*)(outputs + ob + j * 4);
            float4 r;
            r.x = g * acc[j].x + og * o.x;
            r.y = g * acc[j].y + og * o.y;
            r.z = g * acc[j].z + og * o.z;
            r.w = g * acc[j].w + og * o.w;
            *(float4*)(out + ob + j * 4) = r;
        }
    }
}

extern "C" void kernel_launch(void* const* d_in, const int* in_sizes, int n_in,
                              void* d_out, int out_size, void* d_ws, size_t ws_size,
                              hipStream_t stream) {
    (void)in_sizes; (void)n_in; (void)out_size; (void)d_ws; (void)ws_size;
    const float* query   = (const float*)d_in[1];
    const float* outputs = (const float*)d_in[4];
    const float* gate    = (const float*)d_in[5];
    const float* kmem    = (const float*)d_in[6];
    const float* vmem    = (const float*)d_in[7];
    float* out = (float*)d_out;
    dim3 grid(NH * (SEQ / TQ));  // 256 workgroups, exactly 1 per CU
    praxis_fused<<<grid, NTHR, 0, stream>>>(query, outputs, gate, kmem, vmem, out);
}